// Round 10
// baseline (849.845 us; speedup 1.0000x reference)
//
#include <hip/hip_runtime.h>
#include <hip/hip_fp16.h>

constexpr int N    = 100000;
constexpr int E    = 1600000;
constexpr int FIN  = 9;
constexpr int OUTF = 6;
constexpr int G    = 1024;
constexpr int NPB  = 256;                    // nodes per bucket
constexpr int NB   = (N + NPB - 1) / NPB;    // 391 buckets
constexpr int CH   = 2048;                   // edges per chunk
constexpr int NCH  = (E + CH - 1) / CH;      // 782
constexpr int CSRCAP = E + 120000;           // padded csr capacity
constexpr int EBUF  = 5888;                  // passB LDS edge stash
constexpr int NSL   = 4;                     // feature slices (16 feats = 3.2MB fp16 each)

__device__ __forceinline__ void atomAddF(float* p, float v) { unsafeAtomicAdd(p, v); }

// ---- CSR build step 1: bucket histogram (dst>>8) ----
__global__ __launch_bounds__(256) void histB(const int* __restrict__ dst, int* __restrict__ gcnt)
{
    __shared__ int h[NB];
    int t = threadIdx.x;
    for (int i = t; i < NB; i += 256) h[i] = 0;
    __syncthreads();
    int base = blockIdx.x * CH;
#pragma unroll
    for (int i = 0; i < 8; i++) {
        int e = base + i * 256 + t;
        if (e < E) atomicAdd(&h[dst[e] >> 8], 1);
    }
    __syncthreads();
    for (int i = t; i < NB; i += 256) if (h[i]) atomicAdd(&gcnt[i], h[i]);
}

// ---- step 2: scan padded bucket reservations -> bstart + write cursor ----
__global__ __launch_bounds__(512) void scanB(const int* __restrict__ gcnt,
    int* __restrict__ bstart, int* __restrict__ cursor)
{
    __shared__ int sa[512], sb[512];
    int t = threadIdx.x;
    int v0 = (t < NB) ? ((gcnt[t] + NPB + 8) & ~1) : 0;
    sa[t] = v0;
    __syncthreads();
    int* cur = sa; int* nxt = sb;
    for (int o = 1; o < 512; o <<= 1) {
        int v = cur[t];
        if (t >= o) v += cur[t - o];
        nxt[t] = v;
        __syncthreads();
        int* tmp = cur; cur = nxt; nxt = tmp;
    }
    if (t < NB) { int ex = cur[t] - v0; bstart[t] = ex; cursor[t] = ex; }
}

// ---- step 3: scatter packed edges (src | dloc<<24, w) into bucket-grouped array ----
__global__ __launch_bounds__(256) void passA(const int* __restrict__ src, const int* __restrict__ dst,
    const float* __restrict__ ew, int* __restrict__ cursor, int2* __restrict__ bucketed)
{
    __shared__ int h[NB];
    __shared__ int hb[NB];
    int t = threadIdx.x;
    for (int i = t; i < NB; i += 256) h[i] = 0;
    __syncthreads();
    int base = blockIdx.x * CH;
    int myS[8], myD[8], rk[8]; float myW[8];
#pragma unroll
    for (int i = 0; i < 8; i++) {
        int e = base + i * 256 + t;
        if (e < E) {
            myS[i] = src[e]; myD[i] = dst[e]; myW[i] = ew[e];
            rk[i] = atomicAdd(&h[myD[i] >> 8], 1);
        } else myD[i] = -1;
    }
    __syncthreads();
    for (int i = t; i < NB; i += 256) hb[i] = h[i] ? atomicAdd(&cursor[i], h[i]) : 0;
    __syncthreads();
#pragma unroll
    for (int i = 0; i < 8; i++) if (myD[i] >= 0) {
        int packed = myS[i] | ((myD[i] & 255) << 24);
        bucketed[hb[myD[i] >> 8] + rk[i]] = make_int2(packed, __float_as_int(myW[i]));
    }
}

// ---- step 4: per-bucket local CSR -> split arrays csrs(int) + csrw(fp16 as ushort) ----
__global__ __launch_bounds__(NPB) void passB(const int* __restrict__ gcnt, const int* __restrict__ bstart,
    const int2* __restrict__ bucketed, int* __restrict__ ebeg, int* __restrict__ eend,
    int* __restrict__ csrs, unsigned short* __restrict__ csrw)
{
    __shared__ int2 ebuf[EBUF];
    __shared__ int cl[NPB], sa[NPB], sb[NPB], curs[NPB];
    int b = blockIdx.x, t = threadIdx.x;
    int node0 = b * NPB;
    int nnode = min(NPB, N - node0);
    int cnt = gcnt[b], base = bstart[b];
    bool fits = (cnt <= EBUF);
    cl[t] = 0;
    __syncthreads();
    for (int e = t; e < cnt; e += NPB) {
        int2 r = bucketed[base + e];
        if (fits) ebuf[e] = r;
        atomicAdd(&cl[((unsigned)r.x) >> 24], 1);
    }
    __syncthreads();
    int deg = cl[t];
    int pc = (deg + 1) & ~1;
    int* cur = sa; int* nxt = sb;
    cur[t] = pc;
    __syncthreads();
    for (int o = 1; o < NPB; o <<= 1) {
        int v = cur[t];
        if (t >= o) v += cur[t - o];
        nxt[t] = v;
        __syncthreads();
        int* tmp = cur; cur = nxt; nxt = tmp;
    }
    int off = cur[t] - pc;
    if (t < nnode) { ebeg[node0 + t] = base + off; eend[node0 + t] = base + off + deg; }
    curs[t] = off;
    __syncthreads();
    for (int e = t; e < cnt; e += NPB) {
        int2 r = fits ? ebuf[e] : bucketed[base + e];
        int dl = ((unsigned)r.x) >> 24;
        int pos = base + atomicAdd(&curs[dl], 1);
        csrs[pos] = r.x & 0x00FFFFFF;
        __half hw = __float2half(__int_as_float(r.y));
        csrw[pos] = *(const unsigned short*)&hw;
    }
    __syncthreads();
    if (t < nnode && (deg & 1)) { csrs[base + off + deg] = 0; csrw[base + off + deg] = 0; }
    if (t < 4) { csrs[base + cur[NPB-1] + t] = 0; csrw[base + cur[NPB-1] + t] = 0; }
}

// ---- fused projection: P(sliced fp16) = BNin@Wrel ; Hout(fp16 rowmajor) = BNin@Wroot + b ----
// P slice layout: P[ (j>>4)*N*16 + n*16 + (j&15) ]  (4 slices x 16 feats, 3.2MB each)
template<int K, int HIN>
__global__ __launch_bounds__(256) void proj(const void* Ain_,
    const float* __restrict__ Wrel, const float* __restrict__ Wroot,
    const float* __restrict__ bias, __half* __restrict__ P, __half* Hout)
{
    int t = threadIdx.x, j = t & 63;
    int nl = __builtin_amdgcn_readfirstlane(t >> 6);
    float wrel[K], wroot[K];
#pragma unroll
    for (int k = 0; k < K; k++) { wrel[k] = Wrel[k * 64 + j]; wroot[k] = Wroot[k * 64 + j]; }
    float bj = bias[j];
    size_t pslot = (size_t)(j >> 4) * N * 16 + (j & 15);
    const int ntiles = N / 4;
    for (int tile = blockIdx.x; tile < ntiles; tile += gridDim.x) {
        int n = tile * 4 + nl;
        float ap = 0.f, ar = bj;
        if constexpr (HIN) {
            const uint4* r4 = (const uint4*)((const __half*)Ain_ + (size_t)n * 64);
#pragma unroll
            for (int q = 0; q < 8; q++) {
                uint4 v = r4[q];
                unsigned arr[4] = {v.x, v.y, v.z, v.w};
#pragma unroll
                for (int c = 0; c < 4; c++) {
                    float2 f = __half22float2(*(const __half2*)&arr[c]);
                    int k = q * 8 + c * 2;
                    ap = fmaf(f.x, wrel[k],     ap); ar = fmaf(f.x, wroot[k],     ar);
                    ap = fmaf(f.y, wrel[k + 1], ap); ar = fmaf(f.y, wroot[k + 1], ar);
                }
            }
        } else {
            const float* r = (const float*)Ain_ + (size_t)n * K;
#pragma unroll
            for (int k = 0; k < K; k++) {
                float h = r[k];
                ap = fmaf(h, wrel[k], ap);
                ar = fmaf(h, wroot[k], ar);
            }
        }
        P[pslot + (size_t)n * 16]    = __float2half(ap);
        Hout[(size_t)n * 64 + j]     = __float2half(ar);
    }
}

// ---- feature-sliced XCD-affine gather ----
// Block's slice q=(blockIdx&7)&3 -> under blockIdx%8 XCD round-robin each XCD
// reads only its 3.2MB P-slice (L2-resident). Wave handles (node, q):
// lane = e_sub*16 + f, 8 edges/iter in two 4-edge chains; clamp+w-zero tails.
template<int EPI>   // 0: write H + BN stats; 1: pool atomics
__global__ __launch_bounds__(256) void gather(const __half* __restrict__ P, __half* H,
    const int* __restrict__ csrs, const unsigned short* __restrict__ csrw,
    const int* __restrict__ ebeg, const int* __restrict__ eend,
    float* __restrict__ stats, const int* __restrict__ batch, float* __restrict__ pool)
{
    int b = blockIdx.x, t = threadIdx.x;
    int lane = t & 63, wave = t >> 6;
    int e_sub = lane >> 4, f = lane & 15;
    int q = (b & 7) & 3;                                  // slice for this block's XCD
    int grp = ((b >> 3) << 1) | ((b & 7) >> 2);           // 0..511 within q-group
    int wvG = grp * 4 + wave;                             // 0..2047 within q-group
    const __half* Pq = P + (size_t)q * N * 16;
    float s1 = 0.f, s2 = 0.f;
    for (int n = wvG; n < N; n += 2048) {
        int beg = ebeg[n], end = eend[n];
        float root = __half2float(H[(size_t)n * 64 + q * 16 + f]);
        float acc0 = 0.f, acc1 = 0.f;
        int c = end - 1;
        for (int k = beg; k < end; k += 8) {
            int i0 = min(k + e_sub, c);
            int i1 = min(k + 4 + e_sub, c);
            int sA = __builtin_nontemporal_load(csrs + i0);
            int sB = __builtin_nontemporal_load(csrs + i1);
            unsigned short uwA = __builtin_nontemporal_load(csrw + i0);
            unsigned short uwB = __builtin_nontemporal_load(csrw + i1);
            float pA = __half2float(Pq[(size_t)sA * 16 + f]);
            float pB = __half2float(Pq[(size_t)sB * 16 + f]);
            float wA = (k + e_sub     < end) ? __half2float(*(const __half*)&uwA) : 0.f;
            float wB = (k + 4 + e_sub < end) ? __half2float(*(const __half*)&uwB) : 0.f;
            acc0 = fmaf(wA, pA, acc0);
            acc1 = fmaf(wB, pB, acc1);
        }
        float r = acc0 + acc1;
        r += __shfl(r, lane ^ 16, 64);                    // reduce over e_sub
        r += __shfl(r, lane ^ 32, 64);
        r += root;
        if constexpr (EPI == 0) {
            if (e_sub == 0) {
                H[(size_t)n * 64 + q * 16 + f] = __float2half(r);
                s1 += r; s2 += r * r;
            }
        } else {
            if (e_sub == 0) atomAddF(&pool[batch[n] * 64 + q * 16 + f], r);
        }
    }
    if constexpr (EPI == 0) {
        __shared__ float red1[4][16];
        __shared__ float red2[4][16];
        if (e_sub == 0) { red1[wave][f] = s1; red2[wave][f] = s2; }
        __syncthreads();
        if (t < 16) {
            atomAddF(&stats[q * 16 + t],      red1[0][t] + red1[1][t] + red1[2][t] + red1[3][t]);
            atomAddF(&stats[64 + q * 16 + t], red2[0][t] + red2[1][t] + red2[2][t] + red2[3][t]);
        }
    }
}

// ---- BN finalize + ReLU, in place on fp16 H, 8 halfs/thread ----
__global__ __launch_bounds__(256) void bn_relu(uint4* __restrict__ H4,
    const float* __restrict__ stats, const float* __restrict__ gam, const float* __restrict__ bet)
{
    int i = blockIdx.x * blockDim.x + threadIdx.x;   // over N*8 exactly
    constexpr float invN = 1.0f / (float)N;
    int j0 = (i & 7) * 8;
    uint4 v = H4[i];
    unsigned arr[4] = {v.x, v.y, v.z, v.w};
#pragma unroll
    for (int c = 0; c < 4; c++) {
        float2 f = __half22float2(*(const __half2*)&arr[c]);
        int j = j0 + 2 * c;
        float m0 = stats[j] * invN,     vv0 = stats[64 + j] * invN - m0 * m0;
        float m1 = stats[j + 1] * invN, vv1 = stats[64 + j + 1] * invN - m1 * m1;
        float sc0 = gam[j] * rsqrtf(vv0 + 1e-5f),     sh0 = bet[j] - m0 * sc0;
        float sc1 = gam[j + 1] * rsqrtf(vv1 + 1e-5f), sh1 = bet[j + 1] - m1 * sc1;
        f.x = fmaxf(fmaf(f.x, sc0, sh0), 0.f);
        f.y = fmaxf(fmaf(f.y, sc1, sh1), 0.f);
        __half2 h = __float22half2_rn(f);
        arr[c] = *(const unsigned*)&h;
    }
    H4[i] = make_uint4(arr[0], arr[1], arr[2], arr[3]);
}

// ---- head: mean-pool finalize + 2-layer MLP ----
__global__ __launch_bounds__(64) void head(const float* __restrict__ pool,
    const int* __restrict__ batch, const float* __restrict__ Wl1, const float* __restrict__ bl1,
    const float* __restrict__ Wl2, const float* __restrict__ bl2, float* __restrict__ out)
{
    int g = blockIdx.x, t = threadIdx.x;
    __shared__ float sp[64];
    __shared__ float sz[64];
    __shared__ int scnt;
    if (t == 0) {
        int lo = 0, hi = N;
        while (lo < hi) { int m = (lo + hi) >> 1; if (batch[m] < g) lo = m + 1; else hi = m; }
        int lo2 = lo, hi2 = N;
        while (lo2 < hi2) { int m = (lo2 + hi2) >> 1; if (batch[m] < g + 1) lo2 = m + 1; else hi2 = m; }
        scnt = lo2 - lo;
    }
    __syncthreads();
    float cnt = fmaxf((float)scnt, 1.0f);
    sp[t] = pool[g * 64 + t] / cnt;
    __syncthreads();
    float acc = bl1[t];
#pragma unroll
    for (int k = 0; k < 64; k++) acc = fmaf(sp[k], Wl1[k * 64 + t], acc);
    sz[t] = fmaxf(acc, 0.f);
    __syncthreads();
    if (t < OUTF) {
        float o = bl2[t];
#pragma unroll
        for (int k = 0; k < 64; k++) o = fmaf(sz[k], Wl2[k * OUTF + t], o);
        out[g * OUTF + t] = o;
    }
}

extern "C" void kernel_launch(void* const* d_in, const int* in_sizes, int n_in,
                              void* d_out, int out_size, void* d_ws, size_t ws_size,
                              hipStream_t stream)
{
    const float* x     = (const float*)d_in[0];
    const int*   ei    = (const int*)d_in[1];
    const float* ew    = (const float*)d_in[2];
    const int*   batch = (const int*)d_in[3];
    const float* Wrel0 = (const float*)d_in[4];
    const float* Wroot0= (const float*)d_in[5];
    const float* b0    = (const float*)d_in[6];
    const float* Wrel1 = (const float*)d_in[7];
    const float* Wroot1= (const float*)d_in[8];
    const float* b1    = (const float*)d_in[9];
    const float* Wrel2 = (const float*)d_in[10];
    const float* Wroot2= (const float*)d_in[11];
    const float* b2    = (const float*)d_in[12];
    const float* g0    = (const float*)d_in[13];
    const float* be0   = (const float*)d_in[14];
    const float* g1    = (const float*)d_in[15];
    const float* be1   = (const float*)d_in[16];
    const float* Wl1   = (const float*)d_in[17];
    const float* bl1   = (const float*)d_in[18];
    const float* Wl2   = (const float*)d_in[19];
    const float* bl2   = (const float*)d_in[20];
    const int* srcI = ei;
    const int* dstI = ei + E;

    __half* H      = (__half*)d_ws;                    // N*64 fp16 (12.8 MB)
    __half* P      = H + (size_t)N * 64;               // N*64 fp16 sliced (12.8 MB)
    int*    csrs   = (int*)(P + (size_t)N * 64);       // CSRCAP int (6.9 MB)
    unsigned short* csrw = (unsigned short*)(csrs + CSRCAP);  // CSRCAP fp16 (3.4 MB)
    int*    ebeg   = (int*)(csrw + CSRCAP);            // N
    int*    eend   = ebeg + N;                         // N
    int*    gcnt   = eend + N;                         // NB   -- zero block starts
    float*  stats0 = (float*)(gcnt + NB);              // 128
    float*  stats1 = stats0 + 128;                     // 128
    float*  pool   = stats1 + 128;                     // G*64 -- zero block ends
    int*    bstart = (int*)(pool + G * 64);            // NB
    int*    cursor = bstart + NB;                      // NB
    int2*   bucketed = (int2*)H;                       // E int2 = 12.8MB, aliases H

    hipMemsetAsync(gcnt, 0, (size_t)(NB + 256 + G * 64) * sizeof(int), stream);

    // ---- CSR build (bucketed, by dst) ----
    histB<<<NCH, 256, 0, stream>>>(dstI, gcnt);
    scanB<<<1, 512, 0, stream>>>(gcnt, bstart, cursor);
    passA<<<NCH, 256, 0, stream>>>(srcI, dstI, ew, cursor, bucketed);
    passB<<<NB, NPB, 0, stream>>>(gcnt, bstart, bucketed, ebeg, eend, csrs, csrw);

    // ---- layer 0 ----
    proj<FIN, 0><<<2048, 256, 0, stream>>>(x, Wrel0, Wroot0, b0, P, H);
    gather<0><<<2048, 256, 0, stream>>>(P, H, csrs, csrw, ebeg, eend, stats0, nullptr, nullptr);
    bn_relu<<<N * 8 / 256, 256, 0, stream>>>((uint4*)H, stats0, g0, be0);

    // ---- layer 1 ----
    proj<64, 1><<<2048, 256, 0, stream>>>(H, Wrel1, Wroot1, b1, P, H);
    gather<0><<<2048, 256, 0, stream>>>(P, H, csrs, csrw, ebeg, eend, stats1, nullptr, nullptr);
    bn_relu<<<N * 8 / 256, 256, 0, stream>>>((uint4*)H, stats1, g1, be1);

    // ---- layer 2 + pooling ----
    proj<64, 1><<<2048, 256, 0, stream>>>(H, Wrel2, Wroot2, b2, P, H);
    gather<1><<<2048, 256, 0, stream>>>(P, H, csrs, csrw, ebeg, eend, nullptr, batch, pool);

    // ---- head ----
    head<<<G, 64, 0, stream>>>(pool, batch, Wl1, bl1, Wl2, bl2, (float*)d_out);
}

// Round 12
// 524.290 us; speedup vs baseline: 1.6209x; 1.6209x over previous
//
#include <hip/hip_runtime.h>
#include <hip/hip_fp16.h>

constexpr int N    = 100000;
constexpr int E    = 1600000;
constexpr int FIN  = 9;
constexpr int OUTF = 6;
constexpr int G    = 1024;
constexpr int NPB  = 256;                    // nodes per bucket
constexpr int NB   = (N + NPB - 1) / NPB;    // 391 buckets
constexpr int CH   = 2048;                   // edges per chunk
constexpr int NCH  = (E + CH - 1) / CH;      // 782
constexpr int BCAP = 4864;                   // arena slots/bucket (Poisson(4096)+12 sigma)
constexpr int CBCAP= BCAP + NPB + 8;         // csr slots/bucket (pad-aligned + tail) = 5128
constexpr int EBUF = 5888;                   // passB LDS edge stash (>= BCAP)
constexpr int ZCNT = 256 + G * 64;           // stats0+stats1+pool floats to zero

typedef _Float16 f16x8 __attribute__((ext_vector_type(8)));
typedef float    f32x4 __attribute__((ext_vector_type(4)));

__device__ __forceinline__ void atomAddF(float* p, float v) { unsafeAtomicAdd(p, v); }

// ---- init: arena cursors + zero stats/pool ----
__global__ __launch_bounds__(256) void initK(int* __restrict__ cursor, float* __restrict__ zeros)
{
    int i = blockIdx.x * 256 + threadIdx.x;
    if (i < NB) cursor[i] = i * BCAP;
    if (i < ZCNT) zeros[i] = 0.f;
}

// ---- CSR build pass 1: scatter packed edges (src | dloc<<24, w) into fixed-stride arena ----
__global__ __launch_bounds__(256) void passA(const int* __restrict__ src, const int* __restrict__ dst,
    const float* __restrict__ ew, int* __restrict__ cursor, int2* __restrict__ bucketed)
{
    __shared__ int h[NB];
    __shared__ int hb[NB];
    int t = threadIdx.x;
    for (int i = t; i < NB; i += 256) h[i] = 0;
    __syncthreads();
    int base = blockIdx.x * CH;
    int myS[8], myD[8], rk[8]; float myW[8];
#pragma unroll
    for (int i = 0; i < 8; i++) {
        int e = base + i * 256 + t;
        if (e < E) {
            myS[i] = src[e]; myD[i] = dst[e]; myW[i] = ew[e];
            rk[i] = atomicAdd(&h[myD[i] >> 8], 1);
        } else myD[i] = -1;
    }
    __syncthreads();
    for (int i = t; i < NB; i += 256) hb[i] = h[i] ? atomicAdd(&cursor[i], h[i]) : 0;
    __syncthreads();
#pragma unroll
    for (int i = 0; i < 8; i++) if (myD[i] >= 0) {
        int packed = myS[i] | ((myD[i] & 255) << 24);
        bucketed[hb[myD[i] >> 8] + rk[i]] = make_int2(packed, __float_as_int(myW[i]));
    }
}

// ---- CSR build pass 2: per-bucket local CSR (LDS stash), even-aligned node regions ----
__global__ __launch_bounds__(NPB) void passB(const int* __restrict__ cursor,
    const int2* __restrict__ bucketed, int* __restrict__ ebeg, int* __restrict__ eend,
    int2* __restrict__ csr)
{
    __shared__ int2 ebuf[EBUF];
    __shared__ int cl[NPB], sa[NPB], sb[NPB], curs[NPB];
    int b = blockIdx.x, t = threadIdx.x;
    int node0 = b * NPB;
    int nnode = min(NPB, N - node0);
    int cnt = cursor[b] - b * BCAP;                      // edges landed in this bucket
    int abase = b * BCAP;                                // arena base
    int base = b * CBCAP;                                // csr base
    bool fits = (cnt <= EBUF);                           // always true (cnt <= BCAP)
    cl[t] = 0;
    __syncthreads();
    for (int e = t; e < cnt; e += NPB) {
        int2 r = bucketed[abase + e];
        if (fits) ebuf[e] = r;
        atomicAdd(&cl[((unsigned)r.x) >> 24], 1);
    }
    __syncthreads();
    int deg = cl[t];
    int pc = (deg + 1) & ~1;                             // even-aligned size
    int* cur = sa; int* nxt = sb;
    cur[t] = pc;
    __syncthreads();
    for (int o = 1; o < NPB; o <<= 1) {
        int v = cur[t];
        if (t >= o) v += cur[t - o];
        nxt[t] = v;
        __syncthreads();
        int* tmp = cur; cur = nxt; nxt = tmp;
    }
    int off = cur[t] - pc;
    if (t < nnode) { ebeg[node0 + t] = base + off; eend[node0 + t] = base + off + deg; }
    curs[t] = off;
    __syncthreads();
    for (int e = t; e < cnt; e += NPB) {
        int2 r = fits ? ebuf[e] : bucketed[abase + e];
        int dl = ((unsigned)r.x) >> 24;
        int pos = base + atomicAdd(&curs[dl], 1);
        csr[pos] = make_int2(r.x & 0x00FFFFFF, r.y);
    }
    __syncthreads();
    if (t < nnode && (deg & 1)) csr[base + off + deg] = make_int2(0, 0);   // w=0 pad
    if (t < 4) csr[base + cur[NPB - 1] + t] = make_int2(0, 0);             // tail pads
}

// ---- layer-0 projection (scalar, f32 input x): P = x@Wrel ; Ha = x@Wroot + b ----
__global__ __launch_bounds__(256) void proj0(const float* __restrict__ Ain,
    const float* __restrict__ Wrel, const float* __restrict__ Wroot,
    const float* __restrict__ bias, __half* __restrict__ P, __half* __restrict__ Hout)
{
    int t = threadIdx.x, j = t & 63;
    int nl = __builtin_amdgcn_readfirstlane(t >> 6);
    float wrel[FIN], wroot[FIN];
#pragma unroll
    for (int k = 0; k < FIN; k++) { wrel[k] = Wrel[k * 64 + j]; wroot[k] = Wroot[k * 64 + j]; }
    float bj = bias[j];
    const int ntiles = N / 4;
    for (int tile = blockIdx.x; tile < ntiles; tile += gridDim.x) {
        int n = tile * 4 + nl;
        const float* r = Ain + (size_t)n * FIN;
        float ap = 0.f, ar = bj;
#pragma unroll
        for (int k = 0; k < FIN; k++) {
            float h = r[k];
            ap = fmaf(h, wrel[k], ap);
            ar = fmaf(h, wroot[k], ar);
        }
        P[(size_t)n * 64 + j]    = __float2half(ap);
        Hout[(size_t)n * 64 + j] = __float2half(ar);
    }
}

// ---- weight prep: Wt[c][k] fp16, c<64 -> Wrel[k][c] (P), c>=64 -> Wroot[k][c-64] (H); both layers ----
__global__ __launch_bounds__(256) void wprep(const float* __restrict__ Wrel1, const float* __restrict__ Wroot1,
    const float* __restrict__ Wrel2, const float* __restrict__ Wroot2, __half* __restrict__ Wt)
{
    int i = blockIdx.x * 256 + threadIdx.x;      // over 2*128*64 = 16384
    int layer = i >> 13, r = i & 8191;
    int c = r >> 6, k = r & 63;
    const float* Wrel = layer ? Wrel2 : Wrel1;
    const float* Wroot = layer ? Wroot2 : Wroot1;
    float v = (c < 64) ? Wrel[k * 64 + c] : Wroot[k * 64 + (c - 64)];
    Wt[i] = __float2half(v);
}

// ---- MFMA projection (layers 1,2): P = Hin@Wrel ; Hout = Hin@Wroot + b ----
// 16x16x32 f16 MFMA. A: m=lane&15, k=quad*8+j (f16x8 contiguous from row-major H).
// B: n=lane&15, k=quad*8+j (f16x8 contiguous from Wt[c][k]). C/D: col=lane&15, row=quad*4+reg.
__global__ __launch_bounds__(256) void projm(const __half* __restrict__ Hin, const __half* __restrict__ Wt,
    const float* __restrict__ bias, __half* __restrict__ P, __half* __restrict__ Hout)
{
    int t = threadIdx.x, lane = t & 63;
    int wv = blockIdx.x * 4 + (t >> 6);
    int nw = gridDim.x * 4;
    int n16 = lane & 15, quad = lane >> 4;
    f16x8 bf[8][2];
#pragma unroll
    for (int ct = 0; ct < 8; ct++)
#pragma unroll
        for (int kh = 0; kh < 2; kh++)
            bf[ct][kh] = *(const f16x8*)(Wt + (size_t)(ct * 16 + n16) * 64 + kh * 32 + quad * 8);
    float bcol[4];
#pragma unroll
    for (int i = 0; i < 4; i++) bcol[i] = bias[i * 16 + n16];
    const int NT = N / 16;                        // 6250 node tiles, exact
    for (int tile = wv; tile < NT; tile += nw) {
        int n0 = tile * 16;
        f16x8 a0 = *(const f16x8*)(Hin + (size_t)(n0 + n16) * 64 + quad * 8);
        f16x8 a1 = *(const f16x8*)(Hin + (size_t)(n0 + n16) * 64 + 32 + quad * 8);
        f32x4 acc[8];
#pragma unroll
        for (int ct = 0; ct < 8; ct++) {
            f32x4 c = {0.f, 0.f, 0.f, 0.f};
            c = __builtin_amdgcn_mfma_f32_16x16x32_f16(a0, bf[ct][0], c, 0, 0, 0);
            c = __builtin_amdgcn_mfma_f32_16x16x32_f16(a1, bf[ct][1], c, 0, 0, 0);
            acc[ct] = c;
        }
#pragma unroll
        for (int ct = 0; ct < 8; ct++) {
#pragma unroll
            for (int r = 0; r < 4; r++) {
                int n = n0 + quad * 4 + r;
                if (ct < 4) P[(size_t)n * 64 + ct * 16 + n16] = __float2half(acc[ct][r]);
                else Hout[(size_t)n * 64 + (ct - 4) * 16 + n16] = __float2half(acc[ct][r] + bcol[ct - 4]);
            }
        }
    }
}

// ---- gather-aggregate (R8-proven): H[n] = root + sum_e w_e * P[src_e], node-pair per wave ----
template<int EPI>   // 0: write H + BN stats; 1: pool atomics
__global__ __launch_bounds__(256) void gather(const __half* __restrict__ P, __half* H,
    const int2* __restrict__ csr, const int* __restrict__ ebeg, const int* __restrict__ eend,
    float* __restrict__ stats, const int* __restrict__ batch, float* __restrict__ pool)
{
    int t = threadIdx.x, lane = t & 63;
    int wv = (blockIdx.x * blockDim.x + t) >> 6;
    int nw = (gridDim.x * blockDim.x) >> 6;
    float s1 = 0.f, s2 = 0.f;
    const int NPAIR = N / 2;
    for (int pr = wv; pr < NPAIR; pr += nw) {
        int n0 = 2 * pr, n1 = n0 + 1;
        int b0 = ebeg[n0], m0 = (eend[n0] - b0 + 1) >> 1;
        int b1 = ebeg[n1], m1 = (eend[n1] - b1 + 1) >> 1;
        const int4* q0 = (const int4*)csr + (b0 >> 1);
        const int4* q1 = (const int4*)csr + (b1 >> 1);
        int c0 = max(m0 - 1, 0), c1 = max(m1 - 1, 0);
        float x0 = __half2float(H[(size_t)n0 * 64 + lane]);
        float x1 = __half2float(H[(size_t)n1 * 64 + lane]);
        float a0 = 0.f, a1 = 0.f, a2 = 0.f, a3 = 0.f;
        float a4 = 0.f, a5 = 0.f, a6 = 0.f, a7 = 0.f;
        int mm = max(m0, m1);
        for (int k = 0; k < mm; k += 2) {
            int4 qa = q0[min(k,     c0)];
            int4 qb = q0[min(k + 1, c0)];
            int4 qc = q1[min(k,     c1)];
            int4 qd = q1[min(k + 1, c1)];
            float pa0 = __half2float(P[(size_t)qa.x * 64 + lane]);
            float pa1 = __half2float(P[(size_t)qa.z * 64 + lane]);
            float pb0 = __half2float(P[(size_t)qb.x * 64 + lane]);
            float pb1 = __half2float(P[(size_t)qb.z * 64 + lane]);
            float pc0 = __half2float(P[(size_t)qc.x * 64 + lane]);
            float pc1 = __half2float(P[(size_t)qc.z * 64 + lane]);
            float pd0 = __half2float(P[(size_t)qd.x * 64 + lane]);
            float pd1 = __half2float(P[(size_t)qd.z * 64 + lane]);
            float wa = (k     < m0) ? __int_as_float(qa.y) : 0.f;
            float wA = (k     < m0) ? __int_as_float(qa.w) : 0.f;
            float wb = (k + 1 < m0) ? __int_as_float(qb.y) : 0.f;
            float wB = (k + 1 < m0) ? __int_as_float(qb.w) : 0.f;
            float wc = (k     < m1) ? __int_as_float(qc.y) : 0.f;
            float wC = (k     < m1) ? __int_as_float(qc.w) : 0.f;
            float wd = (k + 1 < m1) ? __int_as_float(qd.y) : 0.f;
            float wD = (k + 1 < m1) ? __int_as_float(qd.w) : 0.f;
            a0 = fmaf(wa, pa0, a0); a1 = fmaf(wA, pa1, a1);
            a2 = fmaf(wb, pb0, a2); a3 = fmaf(wB, pb1, a3);
            a4 = fmaf(wc, pc0, a4); a5 = fmaf(wC, pc1, a5);
            a6 = fmaf(wd, pd0, a6); a7 = fmaf(wD, pd1, a7);
        }
        float r0 = x0 + ((a0 + a1) + (a2 + a3));
        float r1 = x1 + ((a4 + a5) + (a6 + a7));
        if constexpr (EPI == 0) {
            H[(size_t)n0 * 64 + lane] = __float2half(r0);
            H[(size_t)n1 * 64 + lane] = __float2half(r1);
            s1 += r0 + r1; s2 += r0 * r0 + r1 * r1;
        } else {
            atomAddF(&pool[batch[n0] * 64 + lane], r0);
            atomAddF(&pool[batch[n1] * 64 + lane], r1);
        }
    }
    if constexpr (EPI == 0) {
        __shared__ float sred[256];
        sred[t] = s1; __syncthreads();
        if (t < 64) atomAddF(&stats[t], sred[t] + sred[t+64] + sred[t+128] + sred[t+192]);
        __syncthreads();
        sred[t] = s2; __syncthreads();
        if (t < 64) atomAddF(&stats[64 + t], sred[t] + sred[t+64] + sred[t+128] + sred[t+192]);
    }
}

// ---- BN finalize + ReLU, in place on fp16 H, 8 halfs/thread ----
__global__ __launch_bounds__(256) void bn_relu(uint4* __restrict__ H4,
    const float* __restrict__ stats, const float* __restrict__ gam, const float* __restrict__ bet)
{
    int i = blockIdx.x * blockDim.x + threadIdx.x;   // over N*8 exactly
    constexpr float invN = 1.0f / (float)N;
    int j0 = (i & 7) * 8;
    uint4 v = H4[i];
    unsigned arr[4] = {v.x, v.y, v.z, v.w};
#pragma unroll
    for (int c = 0; c < 4; c++) {
        float2 f = __half22float2(*(const __half2*)&arr[c]);
        int j = j0 + 2 * c;
        float m0 = stats[j] * invN,     vv0 = stats[64 + j] * invN - m0 * m0;
        float m1 = stats[j + 1] * invN, vv1 = stats[64 + j + 1] * invN - m1 * m1;
        float sc0 = gam[j] * rsqrtf(vv0 + 1e-5f),     sh0 = bet[j] - m0 * sc0;
        float sc1 = gam[j + 1] * rsqrtf(vv1 + 1e-5f), sh1 = bet[j + 1] - m1 * sc1;
        f.x = fmaxf(fmaf(f.x, sc0, sh0), 0.f);
        f.y = fmaxf(fmaf(f.y, sc1, sh1), 0.f);
        __half2 h = __float22half2_rn(f);
        arr[c] = *(const unsigned*)&h;
    }
    H4[i] = make_uint4(arr[0], arr[1], arr[2], arr[3]);
}

// ---- head: mean-pool finalize + 2-layer MLP ----
__global__ __launch_bounds__(64) void head(const float* __restrict__ pool,
    const int* __restrict__ batch, const float* __restrict__ Wl1, const float* __restrict__ bl1,
    const float* __restrict__ Wl2, const float* __restrict__ bl2, float* __restrict__ out)
{
    int g = blockIdx.x, t = threadIdx.x;
    __shared__ float sp[64];
    __shared__ float sz[64];
    __shared__ int scnt;
    if (t == 0) {
        int lo = 0, hi = N;
        while (lo < hi) { int m = (lo + hi) >> 1; if (batch[m] < g) lo = m + 1; else hi = m; }
        int lo2 = lo, hi2 = N;
        while (lo2 < hi2) { int m = (lo2 + hi2) >> 1; if (batch[m] < g + 1) lo2 = m + 1; else hi2 = m; }
        scnt = lo2 - lo;
    }
    __syncthreads();
    float cnt = fmaxf((float)scnt, 1.0f);
    sp[t] = pool[g * 64 + t] / cnt;
    __syncthreads();
    float acc = bl1[t];
#pragma unroll
    for (int k = 0; k < 64; k++) acc = fmaf(sp[k], Wl1[k * 64 + t], acc);
    sz[t] = fmaxf(acc, 0.f);
    __syncthreads();
    if (t < OUTF) {
        float o = bl2[t];
#pragma unroll
        for (int k = 0; k < 64; k++) o = fmaf(sz[k], Wl2[k * OUTF + t], o);
        out[g * OUTF + t] = o;
    }
}

extern "C" void kernel_launch(void* const* d_in, const int* in_sizes, int n_in,
                              void* d_out, int out_size, void* d_ws, size_t ws_size,
                              hipStream_t stream)
{
    const float* x     = (const float*)d_in[0];
    const int*   ei    = (const int*)d_in[1];
    const float* ew    = (const float*)d_in[2];
    const int*   batch = (const int*)d_in[3];
    const float* Wrel0 = (const float*)d_in[4];
    const float* Wroot0= (const float*)d_in[5];
    const float* b0    = (const float*)d_in[6];
    const float* Wrel1 = (const float*)d_in[7];
    const float* Wroot1= (const float*)d_in[8];
    const float* b1    = (const float*)d_in[9];
    const float* Wrel2 = (const float*)d_in[10];
    const float* Wroot2= (const float*)d_in[11];
    const float* b2    = (const float*)d_in[12];
    const float* g0    = (const float*)d_in[13];
    const float* be0   = (const float*)d_in[14];
    const float* g1    = (const float*)d_in[15];
    const float* be1   = (const float*)d_in[16];
    const float* Wl1   = (const float*)d_in[17];
    const float* bl1   = (const float*)d_in[18];
    const float* Wl2   = (const float*)d_in[19];
    const float* bl2   = (const float*)d_in[20];
    const int* srcI = ei;
    const int* dstI = ei + E;

    __half* Ha     = (__half*)d_ws;                    // N*64 fp16
    __half* Hb     = Ha + (size_t)N * 64;              // N*64 fp16
    __half* P      = Hb + (size_t)N * 64;              // N*64 fp16
    int2*   csr    = (int2*)(P + (size_t)N * 64);      // NB*CBCAP int2 (~16 MB)
    int*    ebeg   = (int*)(csr + (size_t)NB * CBCAP); // N
    int*    eend   = ebeg + N;                         // N
    int*    cursor = eend + N;                         // NB
    float*  stats0 = (float*)(cursor + NB);            // 128 -- zero block start
    float*  stats1 = stats0 + 128;                     // 128
    float*  pool   = stats1 + 128;                     // G*64 -- zero block end
    __half* Wt1    = (__half*)(pool + G * 64);         // 128*64
    __half* Wt2    = Wt1 + 128 * 64;                   // 128*64
    int2*   bucketed = (int2*)Hb;                      // NB*BCAP int2 = 15.2MB, aliases Hb+P (dead until proj0)

    // ---- init + CSR build (bucketed arena, by dst) ----
    initK<<<(ZCNT + 255) / 256, 256, 0, stream>>>(cursor, stats0);
    passA<<<NCH, 256, 0, stream>>>(srcI, dstI, ew, cursor, bucketed);
    passB<<<NB, NPB, 0, stream>>>(cursor, bucketed, ebeg, eend, csr);
    wprep<<<64, 256, 0, stream>>>(Wrel1, Wroot1, Wrel2, Wroot2, Wt1);

    // ---- layer 0 ----
    proj0<<<2048, 256, 0, stream>>>(x, Wrel0, Wroot0, b0, P, Ha);
    gather<0><<<2048, 256, 0, stream>>>(P, Ha, csr, ebeg, eend, stats0, nullptr, nullptr);
    bn_relu<<<N * 8 / 256, 256, 0, stream>>>((uint4*)Ha, stats0, g0, be0);

    // ---- layer 1 ----
    projm<<<1024, 256, 0, stream>>>(Ha, Wt1, b1, P, Hb);
    gather<0><<<2048, 256, 0, stream>>>(P, Hb, csr, ebeg, eend, stats1, nullptr, nullptr);
    bn_relu<<<N * 8 / 256, 256, 0, stream>>>((uint4*)Hb, stats1, g1, be1);

    // ---- layer 2 + pooling ----
    projm<<<1024, 256, 0, stream>>>(Hb, Wt2, b2, P, Ha);
    gather<1><<<2048, 256, 0, stream>>>(P, Ha, csr, ebeg, eend, nullptr, batch, pool);

    // ---- head ----
    head<<<G, 64, 0, stream>>>(pool, batch, Wl1, bl1, Wl2, bl2, (float*)d_out);
}

// Round 13
// 490.070 us; speedup vs baseline: 1.7341x; 1.0698x over previous
//
#include <hip/hip_runtime.h>
#include <hip/hip_fp16.h>

constexpr int N    = 100000;
constexpr int E    = 1600000;
constexpr int FIN  = 9;
constexpr int OUTF = 6;
constexpr int G    = 1024;
constexpr int NPB  = 256;                    // nodes per bucket
constexpr int NB   = (N + NPB - 1) / NPB;    // 391 buckets
constexpr int CH   = 2048;                   // edges per chunk
constexpr int NCH  = (E + CH - 1) / CH;      // 782
constexpr int BCAP = 4864;                   // arena slots/bucket (Poisson(4096)+12 sigma)
constexpr int CBCAP= BCAP + NPB + 8;         // csr slots/bucket = 5128
constexpr int EBUF = 5888;                   // passB LDS edge stash (>= BCAP)
constexpr int ZCNT = 256 + G * 64;           // stats0+stats1+pool floats to zero

typedef _Float16 f16x8 __attribute__((ext_vector_type(8)));
typedef float    f32x4 __attribute__((ext_vector_type(4)));

__device__ __forceinline__ void atomAddF(float* p, float v) { unsafeAtomicAdd(p, v); }

// ---- init: arena cursors + zero stats/pool + x -> fp16 table ----
__global__ __launch_bounds__(256) void initK(int* __restrict__ cursor, float* __restrict__ zeros,
    const float* __restrict__ x, __half* __restrict__ x9)
{
    int i = blockIdx.x * 256 + threadIdx.x;
    if (i < NB) cursor[i] = i * BCAP;
    if (i < ZCNT) zeros[i] = 0.f;
    if (i < N * FIN) x9[i] = __float2half(x[i]);
}

// ---- CSR build pass 1: scatter packed edges (src | dloc<<24, w) into fixed-stride arena ----
__global__ __launch_bounds__(256) void passA(const int* __restrict__ src, const int* __restrict__ dst,
    const float* __restrict__ ew, int* __restrict__ cursor, int2* __restrict__ bucketed)
{
    __shared__ int h[NB];
    __shared__ int hb[NB];
    int t = threadIdx.x;
    for (int i = t; i < NB; i += 256) h[i] = 0;
    __syncthreads();
    int base = blockIdx.x * CH;
    int myS[8], myD[8], rk[8]; float myW[8];
#pragma unroll
    for (int i = 0; i < 8; i++) {
        int e = base + i * 256 + t;
        if (e < E) {
            myS[i] = src[e]; myD[i] = dst[e]; myW[i] = ew[e];
            rk[i] = atomicAdd(&h[myD[i] >> 8], 1);
        } else myD[i] = -1;
    }
    __syncthreads();
    for (int i = t; i < NB; i += 256) hb[i] = h[i] ? atomicAdd(&cursor[i], h[i]) : 0;
    __syncthreads();
#pragma unroll
    for (int i = 0; i < 8; i++) if (myD[i] >= 0) {
        int packed = myS[i] | ((myD[i] & 255) << 24);
        bucketed[hb[myD[i] >> 8] + rk[i]] = make_int2(packed, __float_as_int(myW[i]));
    }
}

// ---- CSR build pass 2: per-bucket local CSR (LDS stash), even-aligned node regions ----
__global__ __launch_bounds__(NPB) void passB(const int* __restrict__ cursor,
    const int2* __restrict__ bucketed, int* __restrict__ ebeg, int* __restrict__ eend,
    int2* __restrict__ csr)
{
    __shared__ int2 ebuf[EBUF];
    __shared__ int cl[NPB], sa[NPB], sb[NPB], curs[NPB];
    int b = blockIdx.x, t = threadIdx.x;
    int node0 = b * NPB;
    int nnode = min(NPB, N - node0);
    int cnt = cursor[b] - b * BCAP;
    int abase = b * BCAP;
    int base = b * CBCAP;
    bool fits = (cnt <= EBUF);
    cl[t] = 0;
    __syncthreads();
    for (int e = t; e < cnt; e += NPB) {
        int2 r = bucketed[abase + e];
        if (fits) ebuf[e] = r;
        atomicAdd(&cl[((unsigned)r.x) >> 24], 1);
    }
    __syncthreads();
    int deg = cl[t];
    int pc = (deg + 1) & ~1;
    int* cur = sa; int* nxt = sb;
    cur[t] = pc;
    __syncthreads();
    for (int o = 1; o < NPB; o <<= 1) {
        int v = cur[t];
        if (t >= o) v += cur[t - o];
        nxt[t] = v;
        __syncthreads();
        int* tmp = cur; cur = nxt; nxt = tmp;
    }
    int off = cur[t] - pc;
    if (t < nnode) { ebeg[node0 + t] = base + off; eend[node0 + t] = base + off + deg; }
    curs[t] = off;
    __syncthreads();
    for (int e = t; e < cnt; e += NPB) {
        int2 r = fits ? ebuf[e] : bucketed[abase + e];
        int dl = ((unsigned)r.x) >> 24;
        int pos = base + atomicAdd(&curs[dl], 1);
        csr[pos] = make_int2(r.x & 0x00FFFFFF, r.y);
    }
    __syncthreads();
    if (t < nnode && (deg & 1)) csr[base + off + deg] = make_int2(0, 0);   // w=0 pad
    if (t < 4) csr[base + cur[NPB - 1] + t] = make_int2(0, 0);             // tail pads
}

// ---- weight prep: Wt[c][k] fp16 for layers 1,2 ----
__global__ __launch_bounds__(256) void wprep(const float* __restrict__ Wrel1, const float* __restrict__ Wroot1,
    const float* __restrict__ Wrel2, const float* __restrict__ Wroot2, __half* __restrict__ Wt)
{
    int i = blockIdx.x * 256 + threadIdx.x;      // over 2*128*64 = 16384
    int layer = i >> 13, r = i & 8191;
    int c = r >> 6, k = r & 63;
    const float* Wrel = layer ? Wrel2 : Wrel1;
    const float* Wroot = layer ? Wroot2 : Wroot1;
    float v = (c < 64) ? Wrel[k * 64 + c] : Wroot[k * 64 + (c - 64)];
    Wt[i] = __float2half(v);
}

// ---- layer-0 gather in 9-dim: agg9[n] = sum_e w_e * x9[src_e]  (x9 table = 1.8MB, L2-resident) ----
// 4 edge-slots x 16 lanes, 2 chains; clamp+w-zero tails; reduce over slots via shfl.
__global__ __launch_bounds__(256) void gather9(const __half* __restrict__ x9,
    const int2* __restrict__ csr, const int* __restrict__ ebeg, const int* __restrict__ eend,
    float* __restrict__ agg9)
{
    int t = threadIdx.x, lane = t & 63;
    int es = lane >> 4, fc = min(lane & 15, FIN - 1);
    int wv = (blockIdx.x * blockDim.x + t) >> 6;
    int nw = (gridDim.x * blockDim.x) >> 6;
    for (int n = wv; n < N; n += nw) {
        int beg = ebeg[n], end = eend[n];
        float a0 = 0.f, a1 = 0.f;
        for (int k = beg; k < end; k += 8) {
            int i0 = min(k + es, end - 1);
            int i1 = min(k + 4 + es, end - 1);
            int2 eA = csr[i0];
            int2 eB = csr[i1];
            float pA = __half2float(x9[(size_t)eA.x * FIN + fc]);
            float pB = __half2float(x9[(size_t)eB.x * FIN + fc]);
            float wA = (k + es     < end) ? __int_as_float(eA.y) : 0.f;
            float wB = (k + 4 + es < end) ? __int_as_float(eB.y) : 0.f;
            a0 = fmaf(wA, pA, a0);
            a1 = fmaf(wB, pB, a1);
        }
        float r = a0 + a1;
        r += __shfl(r, lane ^ 16, 64);
        r += __shfl(r, lane ^ 32, 64);
        if (lane < FIN) agg9[(size_t)n * FIN + lane] = r;
    }
}

// ---- layer-0 projection (post-gather): H0 = agg9@Wrel0 + x@Wroot0 + b0 ; BN stats ----
__global__ __launch_bounds__(256) void proj0post(const float* __restrict__ x,
    const float* __restrict__ agg9, const float* __restrict__ Wrel,
    const float* __restrict__ Wroot, const float* __restrict__ bias,
    __half* __restrict__ H0, float* __restrict__ stats)
{
    int t = threadIdx.x, j = t & 63;
    int nl = __builtin_amdgcn_readfirstlane(t >> 6);
    float wrel[FIN], wroot[FIN];
#pragma unroll
    for (int k = 0; k < FIN; k++) { wrel[k] = Wrel[k * 64 + j]; wroot[k] = Wroot[k * 64 + j]; }
    float bj = bias[j];
    float s1 = 0.f, s2 = 0.f;
    const int ntiles = N / 4;
    for (int tile = blockIdx.x; tile < ntiles; tile += gridDim.x) {
        int n = tile * 4 + nl;
        const float* xr = x + (size_t)n * FIN;
        const float* ar = agg9 + (size_t)n * FIN;
        float acc = bj;
#pragma unroll
        for (int k = 0; k < FIN; k++) {
            acc = fmaf(ar[k], wrel[k], acc);
            acc = fmaf(xr[k], wroot[k], acc);
        }
        H0[(size_t)n * 64 + j] = __float2half(acc);
        s1 += acc; s2 += acc * acc;
    }
    __shared__ float sred[256];
    sred[t] = s1; __syncthreads();
    if (t < 64) atomAddF(&stats[t], sred[t] + sred[t+64] + sred[t+128] + sred[t+192]);
    __syncthreads();
    sred[t] = s2; __syncthreads();
    if (t < 64) atomAddF(&stats[64 + t], sred[t] + sred[t+64] + sred[t+128] + sred[t+192]);
}

// ---- MFMA projection w/ fused BN+ReLU on input: P = BN(Hin)@Wrel ; Hout = BN(Hin)@Wroot + b ----
// A: m=lane&15, k=quad*8+jj (+32 for a1). C/D: col=lane&15, row=quad*4+reg.
__global__ __launch_bounds__(256) void projm(const __half* __restrict__ Hin, const __half* __restrict__ Wt,
    const float* __restrict__ bias, const float* __restrict__ stats,
    const float* __restrict__ gam, const float* __restrict__ bet,
    __half* __restrict__ P, __half* __restrict__ Hout)
{
    int t = threadIdx.x, lane = t & 63;
    int wv = blockIdx.x * 4 + (t >> 6);
    int nw = gridDim.x * 4;
    int n16 = lane & 15, quad = lane >> 4;
    constexpr float invN = 1.0f / (float)N;
    float sc[16], sh[16];
#pragma unroll
    for (int jj = 0; jj < 16; jj++) {
        int k = (jj < 8) ? (quad * 8 + jj) : (32 + quad * 8 + (jj - 8));
        float m = stats[k] * invN;
        float v = stats[64 + k] * invN - m * m;
        sc[jj] = gam[k] * rsqrtf(v + 1e-5f);
        sh[jj] = bet[k] - m * sc[jj];
    }
    f16x8 bf[8][2];
#pragma unroll
    for (int ct = 0; ct < 8; ct++)
#pragma unroll
        for (int kh = 0; kh < 2; kh++)
            bf[ct][kh] = *(const f16x8*)(Wt + (size_t)(ct * 16 + n16) * 64 + kh * 32 + quad * 8);
    float bcol[4];
#pragma unroll
    for (int i = 0; i < 4; i++) bcol[i] = bias[i * 16 + n16];
    const int NT = N / 16;
    for (int tile = wv; tile < NT; tile += nw) {
        int n0 = tile * 16;
        f16x8 r0 = *(const f16x8*)(Hin + (size_t)(n0 + n16) * 64 + quad * 8);
        f16x8 r1 = *(const f16x8*)(Hin + (size_t)(n0 + n16) * 64 + 32 + quad * 8);
        f16x8 a0, a1;
#pragma unroll
        for (int jj = 0; jj < 8; jj++) {
            a0[jj] = (_Float16)fmaxf(fmaf((float)r0[jj], sc[jj],     sh[jj]),     0.f);
            a1[jj] = (_Float16)fmaxf(fmaf((float)r1[jj], sc[jj + 8], sh[jj + 8]), 0.f);
        }
        f32x4 acc[8];
#pragma unroll
        for (int ct = 0; ct < 8; ct++) {
            f32x4 c = {0.f, 0.f, 0.f, 0.f};
            c = __builtin_amdgcn_mfma_f32_16x16x32_f16(a0, bf[ct][0], c, 0, 0, 0);
            c = __builtin_amdgcn_mfma_f32_16x16x32_f16(a1, bf[ct][1], c, 0, 0, 0);
            acc[ct] = c;
        }
#pragma unroll
        for (int ct = 0; ct < 8; ct++) {
#pragma unroll
            for (int r = 0; r < 4; r++) {
                int n = n0 + quad * 4 + r;
                if (ct < 4) P[(size_t)n * 64 + ct * 16 + n16] = __float2half(acc[ct][r]);
                else Hout[(size_t)n * 64 + (ct - 4) * 16 + n16] = __float2half(acc[ct][r] + bcol[ct - 4]);
            }
        }
    }
}

// ---- gather-aggregate (proven): H[n] = root + sum_e w_e * P[src_e], node-pair per wave ----
template<int EPI>   // 0: write H + BN stats; 1: pool atomics
__global__ __launch_bounds__(256) void gather(const __half* __restrict__ P, __half* H,
    const int2* __restrict__ csr, const int* __restrict__ ebeg, const int* __restrict__ eend,
    float* __restrict__ stats, const int* __restrict__ batch, float* __restrict__ pool)
{
    int t = threadIdx.x, lane = t & 63;
    int wv = (blockIdx.x * blockDim.x + t) >> 6;
    int nw = (gridDim.x * blockDim.x) >> 6;
    float s1 = 0.f, s2 = 0.f;
    const int NPAIR = N / 2;
    for (int pr = wv; pr < NPAIR; pr += nw) {
        int n0 = 2 * pr, n1 = n0 + 1;
        int b0 = ebeg[n0], m0 = (eend[n0] - b0 + 1) >> 1;
        int b1 = ebeg[n1], m1 = (eend[n1] - b1 + 1) >> 1;
        const int4* q0 = (const int4*)csr + (b0 >> 1);
        const int4* q1 = (const int4*)csr + (b1 >> 1);
        int c0 = max(m0 - 1, 0), c1 = max(m1 - 1, 0);
        float x0 = __half2float(H[(size_t)n0 * 64 + lane]);
        float x1 = __half2float(H[(size_t)n1 * 64 + lane]);
        float a0 = 0.f, a1 = 0.f, a2 = 0.f, a3 = 0.f;
        float a4 = 0.f, a5 = 0.f, a6 = 0.f, a7 = 0.f;
        int mm = max(m0, m1);
        for (int k = 0; k < mm; k += 2) {
            int4 qa = q0[min(k,     c0)];
            int4 qb = q0[min(k + 1, c0)];
            int4 qc = q1[min(k,     c1)];
            int4 qd = q1[min(k + 1, c1)];
            float pa0 = __half2float(P[(size_t)qa.x * 64 + lane]);
            float pa1 = __half2float(P[(size_t)qa.z * 64 + lane]);
            float pb0 = __half2float(P[(size_t)qb.x * 64 + lane]);
            float pb1 = __half2float(P[(size_t)qb.z * 64 + lane]);
            float pc0 = __half2float(P[(size_t)qc.x * 64 + lane]);
            float pc1 = __half2float(P[(size_t)qc.z * 64 + lane]);
            float pd0 = __half2float(P[(size_t)qd.x * 64 + lane]);
            float pd1 = __half2float(P[(size_t)qd.z * 64 + lane]);
            float wa = (k     < m0) ? __int_as_float(qa.y) : 0.f;
            float wA = (k     < m0) ? __int_as_float(qa.w) : 0.f;
            float wb = (k + 1 < m0) ? __int_as_float(qb.y) : 0.f;
            float wB = (k + 1 < m0) ? __int_as_float(qb.w) : 0.f;
            float wc = (k     < m1) ? __int_as_float(qc.y) : 0.f;
            float wC = (k     < m1) ? __int_as_float(qc.w) : 0.f;
            float wd = (k + 1 < m1) ? __int_as_float(qd.y) : 0.f;
            float wD = (k + 1 < m1) ? __int_as_float(qd.w) : 0.f;
            a0 = fmaf(wa, pa0, a0); a1 = fmaf(wA, pa1, a1);
            a2 = fmaf(wb, pb0, a2); a3 = fmaf(wB, pb1, a3);
            a4 = fmaf(wc, pc0, a4); a5 = fmaf(wC, pc1, a5);
            a6 = fmaf(wd, pd0, a6); a7 = fmaf(wD, pd1, a7);
        }
        float r0 = x0 + ((a0 + a1) + (a2 + a3));
        float r1 = x1 + ((a4 + a5) + (a6 + a7));
        if constexpr (EPI == 0) {
            H[(size_t)n0 * 64 + lane] = __float2half(r0);
            H[(size_t)n1 * 64 + lane] = __float2half(r1);
            s1 += r0 + r1; s2 += r0 * r0 + r1 * r1;
        } else {
            atomAddF(&pool[batch[n0] * 64 + lane], r0);
            atomAddF(&pool[batch[n1] * 64 + lane], r1);
        }
    }
    if constexpr (EPI == 0) {
        __shared__ float sred[256];
        sred[t] = s1; __syncthreads();
        if (t < 64) atomAddF(&stats[t], sred[t] + sred[t+64] + sred[t+128] + sred[t+192]);
        __syncthreads();
        sred[t] = s2; __syncthreads();
        if (t < 64) atomAddF(&stats[64 + t], sred[t] + sred[t+64] + sred[t+128] + sred[t+192]);
    }
}

// ---- head: mean-pool finalize + 2-layer MLP ----
__global__ __launch_bounds__(64) void head(const float* __restrict__ pool,
    const int* __restrict__ batch, const float* __restrict__ Wl1, const float* __restrict__ bl1,
    const float* __restrict__ Wl2, const float* __restrict__ bl2, float* __restrict__ out)
{
    int g = blockIdx.x, t = threadIdx.x;
    __shared__ float sp[64];
    __shared__ float sz[64];
    __shared__ int scnt;
    if (t == 0) {
        int lo = 0, hi = N;
        while (lo < hi) { int m = (lo + hi) >> 1; if (batch[m] < g) lo = m + 1; else hi = m; }
        int lo2 = lo, hi2 = N;
        while (lo2 < hi2) { int m = (lo2 + hi2) >> 1; if (batch[m] < g + 1) lo2 = m + 1; else hi2 = m; }
        scnt = lo2 - lo;
    }
    __syncthreads();
    float cnt = fmaxf((float)scnt, 1.0f);
    sp[t] = pool[g * 64 + t] / cnt;
    __syncthreads();
    float acc = bl1[t];
#pragma unroll
    for (int k = 0; k < 64; k++) acc = fmaf(sp[k], Wl1[k * 64 + t], acc);
    sz[t] = fmaxf(acc, 0.f);
    __syncthreads();
    if (t < OUTF) {
        float o = bl2[t];
#pragma unroll
        for (int k = 0; k < 64; k++) o = fmaf(sz[k], Wl2[k * OUTF + t], o);
        out[g * OUTF + t] = o;
    }
}

extern "C" void kernel_launch(void* const* d_in, const int* in_sizes, int n_in,
                              void* d_out, int out_size, void* d_ws, size_t ws_size,
                              hipStream_t stream)
{
    const float* x     = (const float*)d_in[0];
    const int*   ei    = (const int*)d_in[1];
    const float* ew    = (const float*)d_in[2];
    const int*   batch = (const int*)d_in[3];
    const float* Wrel0 = (const float*)d_in[4];
    const float* Wroot0= (const float*)d_in[5];
    const float* b0    = (const float*)d_in[6];
    const float* Wrel1 = (const float*)d_in[7];
    const float* Wroot1= (const float*)d_in[8];
    const float* b1    = (const float*)d_in[9];
    const float* Wrel2 = (const float*)d_in[10];
    const float* Wroot2= (const float*)d_in[11];
    const float* b2    = (const float*)d_in[12];
    const float* g0    = (const float*)d_in[13];
    const float* be0   = (const float*)d_in[14];
    const float* g1    = (const float*)d_in[15];
    const float* be1   = (const float*)d_in[16];
    const float* Wl1   = (const float*)d_in[17];
    const float* bl1   = (const float*)d_in[18];
    const float* Wl2   = (const float*)d_in[19];
    const float* bl2   = (const float*)d_in[20];
    const int* srcI = ei;
    const int* dstI = ei + E;

    __half* Ha     = (__half*)d_ws;                    // N*64 fp16
    __half* Hb     = Ha + (size_t)N * 64;              // N*64 fp16
    __half* P      = Hb + (size_t)N * 64;              // N*64 fp16
    int2*   csr    = (int2*)(P + (size_t)N * 64);      // NB*CBCAP int2 (~16 MB)
    int*    ebeg   = (int*)(csr + (size_t)NB * CBCAP); // N
    int*    eend   = ebeg + N;                         // N
    int*    cursor = eend + N;                         // NB
    float*  stats0 = (float*)(cursor + NB);            // 128 -- zero block start
    float*  stats1 = stats0 + 128;                     // 128
    float*  pool   = stats1 + 128;                     // G*64 -- zero block end
    __half* Wt1    = (__half*)(pool + G * 64);         // 128*64
    __half* Wt2    = Wt1 + 128 * 64;                   // 128*64
    float*  agg9   = (float*)(Wt2 + 128 * 64);         // N*9 f32 (3.6 MB)
    __half* x9     = (__half*)(agg9 + (size_t)N * FIN);// N*9 fp16 (1.8 MB)
    int2*   bucketed = (int2*)Ha;                      // NB*BCAP int2 = 15.2MB, aliases Ha+Hb (dead until proj0post)

    // ---- init + CSR build (bucketed arena, by dst) ----
    initK<<<(N * FIN + 255) / 256, 256, 0, stream>>>(cursor, stats0, x, x9);
    passA<<<NCH, 256, 0, stream>>>(srcI, dstI, ew, cursor, bucketed);
    passB<<<NB, NPB, 0, stream>>>(cursor, bucketed, ebeg, eend, csr);
    wprep<<<64, 256, 0, stream>>>(Wrel1, Wroot1, Wrel2, Wroot2, Wt1);

    // ---- layer 0: 9-dim gather (L2-resident table) then projection ----
    gather9<<<2048, 256, 0, stream>>>(x9, csr, ebeg, eend, agg9);
    proj0post<<<2048, 256, 0, stream>>>(x, agg9, Wrel0, Wroot0, b0, Ha, stats0);

    // ---- layer 1 (BN0+ReLU fused into projm input) ----
    projm<<<1024, 256, 0, stream>>>(Ha, Wt1, b1, stats0, g0, be0, P, Hb);
    gather<0><<<2048, 256, 0, stream>>>(P, Hb, csr, ebeg, eend, stats1, nullptr, nullptr);

    // ---- layer 2 + pooling (BN1+ReLU fused into projm input) ----
    projm<<<1024, 256, 0, stream>>>(Hb, Wt2, b2, stats1, g1, be1, P, Ha);
    gather<1><<<2048, 256, 0, stream>>>(P, Ha, csr, ebeg, eend, nullptr, batch, pool);

    // ---- head ----
    head<<<G, 64, 0, stream>>>(pool, batch, Wl1, bl1, Wl2, bl2, (float*)d_out);
}

// Round 14
// 479.969 us; speedup vs baseline: 1.7706x; 1.0210x over previous
//
#include <hip/hip_runtime.h>
#include <hip/hip_fp16.h>

constexpr int N    = 100000;
constexpr int E    = 1600000;
constexpr int FIN  = 9;
constexpr int OUTF = 6;
constexpr int G    = 1024;
constexpr int NPB  = 256;                    // nodes per bucket
constexpr int NB   = (N + NPB - 1) / NPB;    // 391 buckets
constexpr int CH   = 2048;                   // edges per chunk
constexpr int NCH  = (E + CH - 1) / CH;      // 782
constexpr int BCAP = 4864;                   // arena slots/bucket (Poisson(4096)+12 sigma)
constexpr int CBCAP= BCAP + NPB + 8;         // csr slots/bucket = 5128
constexpr int EBUF = 5888;                   // passB LDS edge stash (>= BCAP)
constexpr int ZCNT = 256 + G * 64;           // stats0+stats1+pool floats to zero

typedef _Float16 f16x8 __attribute__((ext_vector_type(8)));
typedef float    f32x4 __attribute__((ext_vector_type(4)));

__device__ __forceinline__ void atomAddF(float* p, float v) { unsafeAtomicAdd(p, v); }

// ---- init: arena cursors + zero stats/pool + x -> fp16 table ----
__global__ __launch_bounds__(256) void initK(int* __restrict__ cursor, float* __restrict__ zeros,
    const float* __restrict__ x, __half* __restrict__ x9)
{
    int i = blockIdx.x * 256 + threadIdx.x;
    if (i < NB) cursor[i] = i * BCAP;
    if (i < ZCNT) zeros[i] = 0.f;
    if (i < N * FIN) x9[i] = __float2half(x[i]);
}

// ---- CSR build pass 1: scatter packed edges (src | dloc<<24, w) into fixed-stride arena ----
__global__ __launch_bounds__(256) void passA(const int* __restrict__ src, const int* __restrict__ dst,
    const float* __restrict__ ew, int* __restrict__ cursor, int2* __restrict__ bucketed)
{
    __shared__ int h[NB];
    __shared__ int hb[NB];
    int t = threadIdx.x;
    for (int i = t; i < NB; i += 256) h[i] = 0;
    __syncthreads();
    int base = blockIdx.x * CH;
    int myS[8], myD[8], rk[8]; float myW[8];
#pragma unroll
    for (int i = 0; i < 8; i++) {
        int e = base + i * 256 + t;
        if (e < E) {
            myS[i] = src[e]; myD[i] = dst[e]; myW[i] = ew[e];
            rk[i] = atomicAdd(&h[myD[i] >> 8], 1);
        } else myD[i] = -1;
    }
    __syncthreads();
    for (int i = t; i < NB; i += 256) hb[i] = h[i] ? atomicAdd(&cursor[i], h[i]) : 0;
    __syncthreads();
#pragma unroll
    for (int i = 0; i < 8; i++) if (myD[i] >= 0) {
        int packed = myS[i] | ((myD[i] & 255) << 24);
        bucketed[hb[myD[i] >> 8] + rk[i]] = make_int2(packed, __float_as_int(myW[i]));
    }
}

// ---- CSR build pass 2: per-bucket local CSR (LDS stash), even-aligned node regions ----
__global__ __launch_bounds__(NPB) void passB(const int* __restrict__ cursor,
    const int2* __restrict__ bucketed, int* __restrict__ ebeg, int* __restrict__ eend,
    int2* __restrict__ csr)
{
    __shared__ int2 ebuf[EBUF];
    __shared__ int cl[NPB], sa[NPB], sb[NPB], curs[NPB];
    int b = blockIdx.x, t = threadIdx.x;
    int node0 = b * NPB;
    int nnode = min(NPB, N - node0);
    int cnt = cursor[b] - b * BCAP;
    int abase = b * BCAP;
    int base = b * CBCAP;
    bool fits = (cnt <= EBUF);
    cl[t] = 0;
    __syncthreads();
    for (int e = t; e < cnt; e += NPB) {
        int2 r = bucketed[abase + e];
        if (fits) ebuf[e] = r;
        atomicAdd(&cl[((unsigned)r.x) >> 24], 1);
    }
    __syncthreads();
    int deg = cl[t];
    int pc = (deg + 1) & ~1;
    int* cur = sa; int* nxt = sb;
    cur[t] = pc;
    __syncthreads();
    for (int o = 1; o < NPB; o <<= 1) {
        int v = cur[t];
        if (t >= o) v += cur[t - o];
        nxt[t] = v;
        __syncthreads();
        int* tmp = cur; cur = nxt; nxt = tmp;
    }
    int off = cur[t] - pc;
    if (t < nnode) { ebeg[node0 + t] = base + off; eend[node0 + t] = base + off + deg; }
    curs[t] = off;
    __syncthreads();
    for (int e = t; e < cnt; e += NPB) {
        int2 r = fits ? ebuf[e] : bucketed[abase + e];
        int dl = ((unsigned)r.x) >> 24;
        int pos = base + atomicAdd(&curs[dl], 1);
        csr[pos] = make_int2(r.x & 0x00FFFFFF, r.y);
    }
    __syncthreads();
    if (t < nnode && (deg & 1)) csr[base + off + deg] = make_int2(0, 0);   // w=0 pad
    if (t < 4) csr[base + cur[NPB - 1] + t] = make_int2(0, 0);             // tail pads
}

// ---- weight prep: Wt[c][k] fp16 for layers 1,2 ----
__global__ __launch_bounds__(256) void wprep(const float* __restrict__ Wrel1, const float* __restrict__ Wroot1,
    const float* __restrict__ Wrel2, const float* __restrict__ Wroot2, __half* __restrict__ Wt)
{
    int i = blockIdx.x * 256 + threadIdx.x;      // over 2*128*64 = 16384
    int layer = i >> 13, r = i & 8191;
    int c = r >> 6, k = r & 63;
    const float* Wrel = layer ? Wrel2 : Wrel1;
    const float* Wroot = layer ? Wroot2 : Wroot1;
    float v = (c < 64) ? Wrel[k * 64 + c] : Wroot[k * 64 + (c - 64)];
    Wt[i] = __float2half(v);
}

// ---- layer-0 gather in 9-dim, SOFTWARE-PIPELINED (2-stage csr/x9 rotation) ----
__global__ __launch_bounds__(256) void gather9(const __half* __restrict__ x9,
    const int2* __restrict__ csr, const int* __restrict__ ebeg, const int* __restrict__ eend,
    float* __restrict__ agg9)
{
    int t = threadIdx.x, lane = t & 63;
    int es = lane >> 4, fc = min(lane & 15, FIN - 1);
    int wv = (blockIdx.x * blockDim.x + t) >> 6;
    int nw = (gridDim.x * blockDim.x) >> 6;
    for (int n = wv; n < N; n += nw) {
        int beg = ebeg[n], end = eend[n];
        int last = end - 1;
        // prologue: csr for iters 0,1; x9 for iter 0
        int2 eA0 = csr[min(beg + es,      last)];
        int2 eB0 = csr[min(beg + 4 + es,  last)];
        int2 eA1 = csr[min(beg + 8 + es,  last)];
        int2 eB1 = csr[min(beg + 12 + es, last)];
        __half xA = x9[(size_t)eA0.x * FIN + fc];
        __half xB = x9[(size_t)eB0.x * FIN + fc];
        float a0 = 0.f, a1 = 0.f;
        for (int k = beg; k < end; k += 8) {
            int2 eA2 = csr[min(k + 16 + es, last)];        // csr prefetch iter+2
            int2 eB2 = csr[min(k + 20 + es, last)];
            __half nxA = x9[(size_t)eA1.x * FIN + fc];     // x9 issue for iter+1
            __half nxB = x9[(size_t)eB1.x * FIN + fc];
            float wA = (k + es     < end) ? __int_as_float(eA0.y) : 0.f;
            float wB = (k + 4 + es < end) ? __int_as_float(eB0.y) : 0.f;
            a0 = fmaf(wA, __half2float(xA), a0);           // consume iter k
            a1 = fmaf(wB, __half2float(xB), a1);
            eA0 = eA1; eB0 = eB1; eA1 = eA2; eB1 = eB2;    // rotate
            xA = nxA; xB = nxB;
        }
        float r = a0 + a1;
        r += __shfl(r, lane ^ 16, 64);
        r += __shfl(r, lane ^ 32, 64);
        if (lane < FIN) agg9[(size_t)n * FIN + lane] = r;
    }
}

// ---- layer-0 projection (post-gather): H0 = agg9@Wrel0 + x@Wroot0 + b0 ; BN stats ----
__global__ __launch_bounds__(256) void proj0post(const float* __restrict__ x,
    const float* __restrict__ agg9, const float* __restrict__ Wrel,
    const float* __restrict__ Wroot, const float* __restrict__ bias,
    __half* __restrict__ H0, float* __restrict__ stats)
{
    int t = threadIdx.x, j = t & 63;
    int nl = __builtin_amdgcn_readfirstlane(t >> 6);
    float wrel[FIN], wroot[FIN];
#pragma unroll
    for (int k = 0; k < FIN; k++) { wrel[k] = Wrel[k * 64 + j]; wroot[k] = Wroot[k * 64 + j]; }
    float bj = bias[j];
    float s1 = 0.f, s2 = 0.f;
    const int ntiles = N / 4;
    for (int tile = blockIdx.x; tile < ntiles; tile += gridDim.x) {
        int n = tile * 4 + nl;
        const float* xr = x + (size_t)n * FIN;
        const float* ar = agg9 + (size_t)n * FIN;
        float acc = bj;
#pragma unroll
        for (int k = 0; k < FIN; k++) {
            acc = fmaf(ar[k], wrel[k], acc);
            acc = fmaf(xr[k], wroot[k], acc);
        }
        H0[(size_t)n * 64 + j] = __float2half(acc);
        s1 += acc; s2 += acc * acc;
    }
    __shared__ float sred[256];
    sred[t] = s1; __syncthreads();
    if (t < 64) atomAddF(&stats[t], sred[t] + sred[t+64] + sred[t+128] + sred[t+192]);
    __syncthreads();
    sred[t] = s2; __syncthreads();
    if (t < 64) atomAddF(&stats[64 + t], sred[t] + sred[t+64] + sred[t+128] + sred[t+192]);
}

// ---- MFMA projection w/ fused BN+ReLU on input ----
__global__ __launch_bounds__(256) void projm(const __half* __restrict__ Hin, const __half* __restrict__ Wt,
    const float* __restrict__ bias, const float* __restrict__ stats,
    const float* __restrict__ gam, const float* __restrict__ bet,
    __half* __restrict__ P, __half* __restrict__ Hout)
{
    int t = threadIdx.x, lane = t & 63;
    int wv = blockIdx.x * 4 + (t >> 6);
    int nw = gridDim.x * 4;
    int n16 = lane & 15, quad = lane >> 4;
    constexpr float invN = 1.0f / (float)N;
    float sc[16], sh[16];
#pragma unroll
    for (int jj = 0; jj < 16; jj++) {
        int k = (jj < 8) ? (quad * 8 + jj) : (32 + quad * 8 + (jj - 8));
        float m = stats[k] * invN;
        float v = stats[64 + k] * invN - m * m;
        sc[jj] = gam[k] * rsqrtf(v + 1e-5f);
        sh[jj] = bet[k] - m * sc[jj];
    }
    f16x8 bf[8][2];
#pragma unroll
    for (int ct = 0; ct < 8; ct++)
#pragma unroll
        for (int kh = 0; kh < 2; kh++)
            bf[ct][kh] = *(const f16x8*)(Wt + (size_t)(ct * 16 + n16) * 64 + kh * 32 + quad * 8);
    float bcol[4];
#pragma unroll
    for (int i = 0; i < 4; i++) bcol[i] = bias[i * 16 + n16];
    const int NT = N / 16;
    for (int tile = wv; tile < NT; tile += nw) {
        int n0 = tile * 16;
        f16x8 r0 = *(const f16x8*)(Hin + (size_t)(n0 + n16) * 64 + quad * 8);
        f16x8 r1 = *(const f16x8*)(Hin + (size_t)(n0 + n16) * 64 + 32 + quad * 8);
        f16x8 a0, a1;
#pragma unroll
        for (int jj = 0; jj < 8; jj++) {
            a0[jj] = (_Float16)fmaxf(fmaf((float)r0[jj], sc[jj],     sh[jj]),     0.f);
            a1[jj] = (_Float16)fmaxf(fmaf((float)r1[jj], sc[jj + 8], sh[jj + 8]), 0.f);
        }
        f32x4 acc[8];
#pragma unroll
        for (int ct = 0; ct < 8; ct++) {
            f32x4 c = {0.f, 0.f, 0.f, 0.f};
            c = __builtin_amdgcn_mfma_f32_16x16x32_f16(a0, bf[ct][0], c, 0, 0, 0);
            c = __builtin_amdgcn_mfma_f32_16x16x32_f16(a1, bf[ct][1], c, 0, 0, 0);
            acc[ct] = c;
        }
#pragma unroll
        for (int ct = 0; ct < 8; ct++) {
#pragma unroll
            for (int r = 0; r < 4; r++) {
                int n = n0 + quad * 4 + r;
                if (ct < 4) P[(size_t)n * 64 + ct * 16 + n16] = __float2half(acc[ct][r]);
                else Hout[(size_t)n * 64 + (ct - 4) * 16 + n16] = __float2half(acc[ct][r] + bcol[ct - 4]);
            }
        }
    }
}

// ---- gather-aggregate, SOFTWARE-PIPELINED: csr k+4 prefetch, P k+2 issue, consume k ----
template<int EPI>   // 0: write H + BN stats; 1: pool atomics
__global__ __launch_bounds__(256) void gather(const __half* __restrict__ P, __half* H,
    const int2* __restrict__ csr, const int* __restrict__ ebeg, const int* __restrict__ eend,
    float* __restrict__ stats, const int* __restrict__ batch, float* __restrict__ pool)
{
    int t = threadIdx.x, lane = t & 63;
    int wv = (blockIdx.x * blockDim.x + t) >> 6;
    int nw = (gridDim.x * blockDim.x) >> 6;
    float s1 = 0.f, s2 = 0.f;
    const int NPAIR = N / 2;
    for (int pr = wv; pr < NPAIR; pr += nw) {
        int n0 = 2 * pr, n1 = n0 + 1;
        int b0 = ebeg[n0], m0 = (eend[n0] - b0 + 1) >> 1;
        int b1 = ebeg[n1], m1 = (eend[n1] - b1 + 1) >> 1;
        const int4* q0 = (const int4*)csr + (b0 >> 1);
        const int4* q1 = (const int4*)csr + (b1 >> 1);
        int c0 = max(m0 - 1, 0), c1 = max(m1 - 1, 0);
        float x0 = __half2float(H[(size_t)n0 * 64 + lane]);
        float x1 = __half2float(H[(size_t)n1 * 64 + lane]);
        // prologue: csr packets for iters 0 and 1
        int4 qaA = q0[0],           qbA = q0[min(1, c0)];
        int4 qcA = q1[0],           qdA = q1[min(1, c1)];
        int4 qaB = q0[min(2, c0)],  qbB = q0[min(3, c0)];
        int4 qcB = q1[min(2, c1)],  qdB = q1[min(3, c1)];
        // issue P loads for iter 0
        __half pa0 = P[(size_t)qaA.x * 64 + lane], pa1 = P[(size_t)qaA.z * 64 + lane];
        __half pb0 = P[(size_t)qbA.x * 64 + lane], pb1 = P[(size_t)qbA.z * 64 + lane];
        __half pc0 = P[(size_t)qcA.x * 64 + lane], pc1 = P[(size_t)qcA.z * 64 + lane];
        __half pd0 = P[(size_t)qdA.x * 64 + lane], pd1 = P[(size_t)qdA.z * 64 + lane];
        float a0 = 0.f, a1 = 0.f, a2 = 0.f, a3 = 0.f;
        float a4 = 0.f, a5 = 0.f, a6 = 0.f, a7 = 0.f;
        int mm = max(m0, m1);
        for (int k = 0; k < mm; k += 2) {
            // csr prefetch for iter k+4
            int4 qaC = q0[min(k + 4, c0)], qbC = q0[min(k + 5, c0)];
            int4 qcC = q1[min(k + 4, c1)], qdC = q1[min(k + 5, c1)];
            // P issue for iter k+2 (packets B arrived one iteration ago)
            __half na0 = P[(size_t)qaB.x * 64 + lane], na1 = P[(size_t)qaB.z * 64 + lane];
            __half nb0 = P[(size_t)qbB.x * 64 + lane], nb1 = P[(size_t)qbB.z * 64 + lane];
            __half nc0 = P[(size_t)qcB.x * 64 + lane], nc1 = P[(size_t)qcB.z * 64 + lane];
            __half nd0 = P[(size_t)qdB.x * 64 + lane], nd1 = P[(size_t)qdB.z * 64 + lane];
            // consume iter k
            float wa = (k     < m0) ? __int_as_float(qaA.y) : 0.f;
            float wA = (k     < m0) ? __int_as_float(qaA.w) : 0.f;
            float wb = (k + 1 < m0) ? __int_as_float(qbA.y) : 0.f;
            float wB = (k + 1 < m0) ? __int_as_float(qbA.w) : 0.f;
            float wc = (k     < m1) ? __int_as_float(qcA.y) : 0.f;
            float wC = (k     < m1) ? __int_as_float(qcA.w) : 0.f;
            float wd = (k + 1 < m1) ? __int_as_float(qdA.y) : 0.f;
            float wD = (k + 1 < m1) ? __int_as_float(qdA.w) : 0.f;
            a0 = fmaf(wa, __half2float(pa0), a0); a1 = fmaf(wA, __half2float(pa1), a1);
            a2 = fmaf(wb, __half2float(pb0), a2); a3 = fmaf(wB, __half2float(pb1), a3);
            a4 = fmaf(wc, __half2float(pc0), a4); a5 = fmaf(wC, __half2float(pc1), a5);
            a6 = fmaf(wd, __half2float(pd0), a6); a7 = fmaf(wD, __half2float(pd1), a7);
            // rotate
            qaA = qaB; qbA = qbB; qcA = qcB; qdA = qdB;
            qaB = qaC; qbB = qbC; qcB = qcC; qdB = qdC;
            pa0 = na0; pa1 = na1; pb0 = nb0; pb1 = nb1;
            pc0 = nc0; pc1 = nc1; pd0 = nd0; pd1 = nd1;
        }
        float r0 = x0 + ((a0 + a2) + (a1 + a3));
        float r1 = x1 + ((a4 + a6) + (a5 + a7));
        if constexpr (EPI == 0) {
            H[(size_t)n0 * 64 + lane] = __float2half(r0);
            H[(size_t)n1 * 64 + lane] = __float2half(r1);
            s1 += r0 + r1; s2 += r0 * r0 + r1 * r1;
        } else {
            atomAddF(&pool[batch[n0] * 64 + lane], r0);
            atomAddF(&pool[batch[n1] * 64 + lane], r1);
        }
    }
    if constexpr (EPI == 0) {
        __shared__ float sred[256];
        sred[t] = s1; __syncthreads();
        if (t < 64) atomAddF(&stats[t], sred[t] + sred[t+64] + sred[t+128] + sred[t+192]);
        __syncthreads();
        sred[t] = s2; __syncthreads();
        if (t < 64) atomAddF(&stats[64 + t], sred[t] + sred[t+64] + sred[t+128] + sred[t+192]);
    }
}

// ---- head: mean-pool finalize + 2-layer MLP ----
__global__ __launch_bounds__(64) void head(const float* __restrict__ pool,
    const int* __restrict__ batch, const float* __restrict__ Wl1, const float* __restrict__ bl1,
    const float* __restrict__ Wl2, const float* __restrict__ bl2, float* __restrict__ out)
{
    int g = blockIdx.x, t = threadIdx.x;
    __shared__ float sp[64];
    __shared__ float sz[64];
    __shared__ int scnt;
    if (t == 0) {
        int lo = 0, hi = N;
        while (lo < hi) { int m = (lo + hi) >> 1; if (batch[m] < g) lo = m + 1; else hi = m; }
        int lo2 = lo, hi2 = N;
        while (lo2 < hi2) { int m = (lo2 + hi2) >> 1; if (batch[m] < g + 1) lo2 = m + 1; else hi2 = m; }
        scnt = lo2 - lo;
    }
    __syncthreads();
    float cnt = fmaxf((float)scnt, 1.0f);
    sp[t] = pool[g * 64 + t] / cnt;
    __syncthreads();
    float acc = bl1[t];
#pragma unroll
    for (int k = 0; k < 64; k++) acc = fmaf(sp[k], Wl1[k * 64 + t], acc);
    sz[t] = fmaxf(acc, 0.f);
    __syncthreads();
    if (t < OUTF) {
        float o = bl2[t];
#pragma unroll
        for (int k = 0; k < 64; k++) o = fmaf(sz[k], Wl2[k * OUTF + t], o);
        out[g * OUTF + t] = o;
    }
}

extern "C" void kernel_launch(void* const* d_in, const int* in_sizes, int n_in,
                              void* d_out, int out_size, void* d_ws, size_t ws_size,
                              hipStream_t stream)
{
    const float* x     = (const float*)d_in[0];
    const int*   ei    = (const int*)d_in[1];
    const float* ew    = (const float*)d_in[2];
    const int*   batch = (const int*)d_in[3];
    const float* Wrel0 = (const float*)d_in[4];
    const float* Wroot0= (const float*)d_in[5];
    const float* b0    = (const float*)d_in[6];
    const float* Wrel1 = (const float*)d_in[7];
    const float* Wroot1= (const float*)d_in[8];
    const float* b1    = (const float*)d_in[9];
    const float* Wrel2 = (const float*)d_in[10];
    const float* Wroot2= (const float*)d_in[11];
    const float* b2    = (const float*)d_in[12];
    const float* g0    = (const float*)d_in[13];
    const float* be0   = (const float*)d_in[14];
    const float* g1    = (const float*)d_in[15];
    const float* be1   = (const float*)d_in[16];
    const float* Wl1   = (const float*)d_in[17];
    const float* bl1   = (const float*)d_in[18];
    const float* Wl2   = (const float*)d_in[19];
    const float* bl2   = (const float*)d_in[20];
    const int* srcI = ei;
    const int* dstI = ei + E;

    __half* Ha     = (__half*)d_ws;                    // N*64 fp16
    __half* Hb     = Ha + (size_t)N * 64;              // N*64 fp16
    __half* P      = Hb + (size_t)N * 64;              // N*64 fp16
    int2*   csr    = (int2*)(P + (size_t)N * 64);      // NB*CBCAP int2 (~16 MB)
    int*    ebeg   = (int*)(csr + (size_t)NB * CBCAP); // N
    int*    eend   = ebeg + N;                         // N
    int*    cursor = eend + N;                         // NB
    float*  stats0 = (float*)(cursor + NB);            // 128 -- zero block start
    float*  stats1 = stats0 + 128;                     // 128
    float*  pool   = stats1 + 128;                     // G*64 -- zero block end
    __half* Wt1    = (__half*)(pool + G * 64);         // 128*64
    __half* Wt2    = Wt1 + 128 * 64;                   // 128*64
    float*  agg9   = (float*)(Wt2 + 128 * 64);         // N*9 f32 (3.6 MB)
    __half* x9     = (__half*)(agg9 + (size_t)N * FIN);// N*9 fp16 (1.8 MB)
    int2*   bucketed = (int2*)Ha;                      // NB*BCAP int2 = 15.2MB, aliases Ha+Hb

    // ---- init + CSR build (bucketed arena, by dst) ----
    initK<<<(N * FIN + 255) / 256, 256, 0, stream>>>(cursor, stats0, x, x9);
    passA<<<NCH, 256, 0, stream>>>(srcI, dstI, ew, cursor, bucketed);
    passB<<<NB, NPB, 0, stream>>>(cursor, bucketed, ebeg, eend, csr);
    wprep<<<64, 256, 0, stream>>>(Wrel1, Wroot1, Wrel2, Wroot2, Wt1);

    // ---- layer 0: 9-dim gather (pipelined) then projection ----
    gather9<<<2048, 256, 0, stream>>>(x9, csr, ebeg, eend, agg9);
    proj0post<<<2048, 256, 0, stream>>>(x, agg9, Wrel0, Wroot0, b0, Ha, stats0);

    // ---- layer 1 (BN0+ReLU fused into projm input) ----
    projm<<<1024, 256, 0, stream>>>(Ha, Wt1, b1, stats0, g0, be0, P, Hb);
    gather<0><<<2048, 256, 0, stream>>>(P, Hb, csr, ebeg, eend, stats1, nullptr, nullptr);

    // ---- layer 2 + pooling (BN1+ReLU fused into projm input) ----
    projm<<<1024, 256, 0, stream>>>(Hb, Wt2, b2, stats1, g1, be1, P, Ha);
    gather<1><<<2048, 256, 0, stream>>>(P, Ha, csr, ebeg, eend, nullptr, batch, pool);

    // ---- head ----
    head<<<G, 64, 0, stream>>>(pool, batch, Wl1, bl1, Wl2, bl2, (float*)d_out);
}